// Round 14
// baseline (494.110 us; speedup 1.0000x reference)
//
#include <hip/hip_runtime.h>
#include <hip/hip_cooperative_groups.h>

namespace cg = cooperative_groups;

#define HW_ 1024

typedef __attribute__((ext_vector_type(8))) short bf16x8;   // 8 bf16 = 4 VGPRs
typedef __attribute__((ext_vector_type(4))) short bf16x4;   // 8 B
typedef __attribute__((ext_vector_type(4))) float f32x4;

__device__ inline unsigned short f2bf(float f) {            // RNE f32->bf16
  unsigned int u = __float_as_uint(f);
  u += 0x7FFF + ((u >> 16) & 1);
  return (unsigned short)(u >> 16);
}
__device__ inline unsigned short f2bf_fast(float f) {       // ties-away (2 ops)
  return (unsigned short)((__float_as_uint(f) + 0x8000u) >> 16);
}
__device__ inline float bf2f(unsigned short h) {
  return __uint_as_float(((unsigned int)h) << 16);
}
__device__ inline void async_copy16(const void* g, void* l) {
  __builtin_amdgcn_global_load_lds(
      (const __attribute__((address_space(1))) unsigned int*)g,
      (__attribute__((address_space(3))) unsigned int*)l, 16, 0, 0);
}

// ===========================================================================
// Phase bodies — byte-identical logic to the six r13 kernels, virtual-block
// remapped, LDS through a 33792-B union (max: gemm_kv 2x32x264 shorts).
// ===========================================================================

// --- phase 1: prep (2432 vblocks) ------------------------------------------
__device__ __forceinline__ void prep_body(
    int bid, unsigned char* SM, const float* kv,
    const float* W0, const float* W1, const float* W2, const float* W3,
    const float* Woff1, short* WH, short* WL, short* wb, float* kvT)
{
  const int t = threadIdx.x;
  if (bid < 256) {                      // kvT: (b,c,p) -> (b,p,c) f32 via LDS
    float (*T)[33] = (float (*)[33])SM;
    int b = bid >> 5, p0 = (bid & 31) * 32;
    int pp = t & 31, cg_ = t >> 5;
#pragma unroll
    for (int i = 0; i < 32; ++i) {
      int c = cg_ * 32 + i;
      T[c][pp] = kv[((size_t)(b * 256 + c)) * HW_ + p0 + pp];
    }
    __syncthreads();
#pragma unroll
    for (int r = 0; r < 8; ++r) {
      int e = t + 256 * r;
      int c4 = (e & 63) * 4, pp2 = e >> 6;
      float4 v4;
      v4.x = T[c4 + 0][pp2];
      v4.y = T[c4 + 1][pp2];
      v4.z = T[c4 + 2][pp2];
      v4.w = T[c4 + 3][pp2];
      *(float4*)&kvT[((size_t)(b * 1024 + p0 + pp2)) * 256 + c4] = v4;
    }
  } else if (bid < 1280) {              // wsplit
    int b2 = bid - 256;
    int mat = b2 >> 8;
    int idx = (b2 & 255) * 256 + t;
    const float* W = (mat == 0) ? W0 : (mat == 1) ? W1 : (mat == 2) ? W2 : W3;
    float f = W[idx];
    unsigned short h = f2bf(f);
    WH[mat * 65536 + idx] = (short)h;
    WL[mat * 65536 + idx] = (short)f2bf(f - bf2f(h));
  } else {                              // conv weights
    int e = (bid - 1280) * 256 + t;     // < 294912
    int c = e & 255;
    int o = (e >> 8) & 127;
    int tap = e >> 15;
    wb[e] = (short)f2bf(Woff1[((size_t)(o * 256 + c)) * 9 + tap]);
  }
}

// --- phase 2: gemm_q (256 vblocks, MODE 0) ---------------------------------
__device__ __forceinline__ void gemm_q_body(
    int bx, unsigned char* SM, const short* Wh, const short* Wl,
    const float* Xf, short* Yt, short* Yh2, short* Yl2)
{
  short (*Bsh)[40] = (short (*)[40])SM;          // 2560 B
  short (*Bsl)[40] = (short (*)[40])(SM + 2560); // 2560 B
  const int t    = threadIdx.x;
  const int w    = t >> 6;
  const int lane = t & 63;
  const int ln   = lane & 15;
  const int qd   = lane >> 4;
  const int bp0  = bx * 32;
  const int om   = w * 64;
  const int bB   = bp0 >> 10, p0l = bp0 & 1023;

  f32x4 acc[4][2] = {};
#pragma unroll
  for (int k0 = 0; k0 < 256; k0 += 32) {
    bf16x8 Ah[4], Al[4], Bh[2], Bl[2];
    {
      __syncthreads();
      int pp = t & 31, cg_ = t >> 5;
      float fv[4];
#pragma unroll
      for (int j = 0; j < 4; ++j)
        fv[j] = Xf[((size_t)(bB * 256 + k0 + cg_ * 4 + j)) * HW_ + p0l + pp];
      bf16x4 h4, l4;
#pragma unroll
      for (int j = 0; j < 4; ++j) {
        unsigned short h = f2bf(fv[j]);
        h4[j] = (short)h;
        l4[j] = (short)f2bf(fv[j] - bf2f(h));
      }
      *(bf16x4*)&Bsh[pp][cg_ * 4] = h4;
      *(bf16x4*)&Bsl[pp][cg_ * 4] = l4;
      __syncthreads();
    }
#pragma unroll
    for (int mt = 0; mt < 4; ++mt) {
      size_t wi = ((size_t)(om + mt * 16 + ln)) * 256 + k0 + qd * 8;
      Ah[mt] = *(const bf16x8*)&Wh[wi];
      Al[mt] = *(const bf16x8*)&Wl[wi];
    }
#pragma unroll
    for (int nt = 0; nt < 2; ++nt) {
      Bh[nt] = *(const bf16x8*)&Bsh[nt * 16 + ln][qd * 8];
      Bl[nt] = *(const bf16x8*)&Bsl[nt * 16 + ln][qd * 8];
    }
#pragma unroll
    for (int mt = 0; mt < 4; ++mt)
#pragma unroll
      for (int nt = 0; nt < 2; ++nt) {
        acc[mt][nt] = __builtin_amdgcn_mfma_f32_16x16x32_bf16(Ah[mt], Bh[nt], acc[mt][nt], 0, 0, 0);
        acc[mt][nt] = __builtin_amdgcn_mfma_f32_16x16x32_bf16(Ah[mt], Bl[nt], acc[mt][nt], 0, 0, 0);
        acc[mt][nt] = __builtin_amdgcn_mfma_f32_16x16x32_bf16(Al[mt], Bh[nt], acc[mt][nt], 0, 0, 0);
      }
  }

  const float sc = 0.25506063286f;   // (1/sqrt32)*log2(e)
#pragma unroll
  for (int mt = 0; mt < 4; ++mt)
#pragma unroll
    for (int nt = 0; nt < 2; ++nt) {
      int bp = bp0 + nt * 16 + ln;
      int b = bp >> 10, p = bp & 1023;
#pragma unroll
      for (int i = 0; i < 4; ++i) {
        int o = om + mt * 16 + qd * 4 + i;
        int h = o >> 5, d = o & 31;
        Yt[(((size_t)(b * 8 + h)) * 1024 + p) * 32 + d] = (short)f2bf(acc[mt][nt][i] * sc);
      }
      int ob = om + mt * 16 + qd * 4;
      bf16x4 h4, l4;
#pragma unroll
      for (int i = 0; i < 4; ++i) {
        float f = acc[mt][nt][i];
        unsigned short h = f2bf(f);
        h4[i] = (short)h;
        l4[i] = (short)f2bf(f - bf2f(h));
      }
      *(bf16x4*)&Yh2[(size_t)bp * 256 + ob] = h4;
      *(bf16x4*)&Yl2[(size_t)bp * 256 + ob] = l4;
    }
}

// --- phase 3: conv3x3 + offset head (256 vblocks) --------------------------
__device__ __forceinline__ void conv_body(
    int vb, unsigned char* SM, const short* wb, const float* bias,
    const float* W2, const float* b2,
    const short* xh, const short* xl, float2* coords)
{
  typedef short xs_t[3][34][32];
  xs_t* Xs = (xs_t*)SM;                            // 2*13056/2... = 13056 B
  float (*red)[32][2] = (float (*)[32][2])(SM + 13056);  // 1024 B
  const int t    = threadIdx.x;
  const int w    = t >> 6;
  const int lane = t & 63;
  const int ln   = lane & 15;
  const int qd   = lane >> 4;
  const int y0   = vb & 31;
  const int b    = vb >> 5;
  const int o0   = w * 32;

  f32x4 acc[2][2] = {};

  for (int c0 = 0; c0 < 256; c0 += 32) {
    __syncthreads();
#pragma unroll
    for (int i = 0; i < 3; ++i) {
      int e   = t + 256 * i;
      int oct = e & 3;
      int x   = (e >> 2) & 31;
      int r   = (e >> 7) % 3;
      int hl  = e / 384;
      int yy  = y0 + r - 1;
      bf16x8 val = {};
      if (yy >= 0 && yy < 32) {
        const short* src = hl ? xl : xh;
        val = *(const bf16x8*)&src[((size_t)((b * 32 + yy) * 32 + x)) * 256 + c0 + oct * 8];
      }
      *(bf16x8*)&Xs[hl][r][x + 1][oct * 8] = val;
    }
    if (t < 48) {
      int oct = t & 3;
      int col = ((t >> 2) & 1) ? 33 : 0;
      int r   = (t >> 3) % 3;
      int hl  = t / 24;
      bf16x8 z = {};
      *(bf16x8*)&Xs[hl][r][col][oct * 8] = z;
    }
    __syncthreads();

#pragma unroll
    for (int tap = 0; tap < 9; ++tap) {
      const int ky = tap / 3, kx = tap % 3;
      bf16x8 afr[2];
#pragma unroll
      for (int m = 0; m < 2; ++m)
        afr[m] = *(const bf16x8*)&wb[((size_t)(tap * 128 + o0 + m * 16 + ln)) * 256
                                     + c0 + qd * 8];
#pragma unroll
      for (int nt = 0; nt < 2; ++nt) {
        int hc = nt * 16 + ln + kx;
        bf16x8 bh = *(const bf16x8*)&Xs[0][ky][hc][qd * 8];
        bf16x8 bl = *(const bf16x8*)&Xs[1][ky][hc][qd * 8];
#pragma unroll
        for (int m = 0; m < 2; ++m) {
          acc[m][nt] = __builtin_amdgcn_mfma_f32_16x16x32_bf16(afr[m], bh, acc[m][nt], 0, 0, 0);
          acc[m][nt] = __builtin_amdgcn_mfma_f32_16x16x32_bf16(afr[m], bl, acc[m][nt], 0, 0, 0);
        }
      }
    }
  }

  float ps0[2] = {0.f, 0.f}, ps1[2] = {0.f, 0.f};
#pragma unroll
  for (int m = 0; m < 2; ++m)
#pragma unroll
    for (int i = 0; i < 4; ++i) {
      int o = o0 + m * 16 + qd * 4 + i;
      float bo = bias[o];
      float w2a = W2[o], w2b = W2[128 + o];
#pragma unroll
      for (int nt = 0; nt < 2; ++nt) {
        float h = fmaxf(acc[m][nt][i] + bo, 0.f);
        ps0[nt] += w2a * h;
        ps1[nt] += w2b * h;
      }
    }
#pragma unroll
  for (int msk = 16; msk < 64; msk <<= 1) {
    ps0[0] += __shfl_xor(ps0[0], msk, 64);
    ps0[1] += __shfl_xor(ps0[1], msk, 64);
    ps1[0] += __shfl_xor(ps1[0], msk, 64);
    ps1[1] += __shfl_xor(ps1[1], msk, 64);
  }
  if (qd == 0) {
#pragma unroll
    for (int nt = 0; nt < 2; ++nt) {
      red[w][nt * 16 + ln][0] = ps0[nt];
      red[w][nt * 16 + ln][1] = ps1[nt];
    }
  }
  __syncthreads();
  if (t < 32) {
    int x = t;
    float s0 = red[0][x][0] + red[1][x][0] + red[2][x][0] + red[3][x][0] + b2[0];
    float s1 = red[0][x][1] + red[1][x][1] + red[2][x][1] + red[3][x][1] + b2[1];
    float gx = -1.f + 2.f * (float)x / 31.f;
    float gy = -1.f + 2.f * (float)y0 / 31.f;
    float vx = gx + 0.1f * s0;
    float vy = gy + 0.1f * s1;
    float px = fminf(fmaxf((vx + 1.f) * 0.5f * 31.f, 0.f), 31.f);
    float py = fminf(fmaxf((vy + 1.f) * 0.5f * 31.f, 0.f), 31.f);
    coords[b * 1024 + y0 * 32 + x] = make_float2(px, py);
  }
  __syncthreads();
}

// --- phase 4: gemm_kv (512 vblocks) ----------------------------------------
__device__ __forceinline__ void gemm_kv_body(
    int vb, unsigned char* SM, const short* WH, const short* WL,
    const float* kvT, const float2* coords, short* kt, short* vt)
{
  short (*XsH)[264] = (short (*)[264])SM;            // 16896 B
  short (*XsL)[264] = (short (*)[264])(SM + 16896);  // 16896 B
  const int t   = threadIdx.x;
  const int bp0 = (vb & 255) * 32;
  const int b   = bp0 >> 10;
  const int mat = vb >> 8;           // 0 = K, 1 = V

#pragma unroll
  for (int it = 0; it < 4; ++it) {
    int e = t + 256 * it;
    int oct = e & 31, row = e >> 5;
    float2 cd = coords[bp0 + row];
    float x0f = floorf(cd.x), y0f = floorf(cd.y);
    float wx = cd.x - x0f, wy = cd.y - y0f;
    int x0 = (int)x0f, y0 = (int)y0f;
    int x1 = min(x0 + 1, 31), y1 = min(y0 + 1, 31);
    float w00 = (1.f - wx) * (1.f - wy), w01 = wx * (1.f - wy);
    float w10 = (1.f - wx) * wy,         w11 = wx * wy;
    const float* r00 = &kvT[((size_t)(b * 1024 + y0 * 32 + x0)) * 256 + oct * 8];
    const float* r01 = &kvT[((size_t)(b * 1024 + y0 * 32 + x1)) * 256 + oct * 8];
    const float* r10 = &kvT[((size_t)(b * 1024 + y1 * 32 + x0)) * 256 + oct * 8];
    const float* r11 = &kvT[((size_t)(b * 1024 + y1 * 32 + x1)) * 256 + oct * 8];
    float4 a00 = *(const float4*)r00, b00 = *(const float4*)(r00 + 4);
    float4 a01 = *(const float4*)r01, b01 = *(const float4*)(r01 + 4);
    float4 a10 = *(const float4*)r10, b10 = *(const float4*)(r10 + 4);
    float4 a11 = *(const float4*)r11, b11 = *(const float4*)(r11 + 4);
    float v[8];
    v[0] = a00.x * w00 + a01.x * w01 + a10.x * w10 + a11.x * w11;
    v[1] = a00.y * w00 + a01.y * w01 + a10.y * w10 + a11.y * w11;
    v[2] = a00.z * w00 + a01.z * w01 + a10.z * w10 + a11.z * w11;
    v[3] = a00.w * w00 + a01.w * w01 + a10.w * w10 + a11.w * w11;
    v[4] = b00.x * w00 + b01.x * w01 + b10.x * w10 + b11.x * w11;
    v[5] = b00.y * w00 + b01.y * w01 + b10.y * w10 + b11.y * w11;
    v[6] = b00.z * w00 + b01.z * w01 + b10.z * w10 + b11.z * w11;
    v[7] = b00.w * w00 + b01.w * w01 + b10.w * w10 + b11.w * w11;
    bf16x8 h8, l8;
#pragma unroll
    for (int j = 0; j < 8; ++j) {
      unsigned short h = f2bf(v[j]);
      h8[j] = (short)h;
      l8[j] = (short)f2bf(v[j] - bf2f(h));
    }
    *(bf16x8*)&XsH[row][oct * 8] = h8;
    *(bf16x8*)&XsL[row][oct * 8] = l8;
  }
  __syncthreads();

  const int w    = t >> 6;
  const int lane = t & 63;
  const int ln   = lane & 15;
  const int qd   = lane >> 4;
  const short* WAh = WH + (mat ? 131072 : 65536);   // Wv : Wk
  const short* WAl = WL + (mat ? 131072 : 65536);
  const int om = w * 64;

  f32x4 acc[4][2] = {};
#pragma unroll
  for (int k0 = 0; k0 < 256; k0 += 32) {
    bf16x8 Bh[2], Bl[2];
#pragma unroll
    for (int nt = 0; nt < 2; ++nt) {
      Bh[nt] = *(const bf16x8*)&XsH[nt * 16 + ln][k0 + qd * 8];
      Bl[nt] = *(const bf16x8*)&XsL[nt * 16 + ln][k0 + qd * 8];
    }
#pragma unroll
    for (int mt = 0; mt < 4; ++mt) {
      size_t wi = ((size_t)(om + mt * 16 + ln)) * 256 + k0 + qd * 8;
      bf16x8 Ah = *(const bf16x8*)&WAh[wi];
      bf16x8 Al = *(const bf16x8*)&WAl[wi];
#pragma unroll
      for (int nt = 0; nt < 2; ++nt) {
        acc[mt][nt] = __builtin_amdgcn_mfma_f32_16x16x32_bf16(Ah, Bh[nt], acc[mt][nt], 0, 0, 0);
        acc[mt][nt] = __builtin_amdgcn_mfma_f32_16x16x32_bf16(Ah, Bl[nt], acc[mt][nt], 0, 0, 0);
        acc[mt][nt] = __builtin_amdgcn_mfma_f32_16x16x32_bf16(Al, Bh[nt], acc[mt][nt], 0, 0, 0);
      }
    }
  }

#pragma unroll
  for (int mt = 0; mt < 4; ++mt)
#pragma unroll
    for (int nt = 0; nt < 2; ++nt) {
      int p  = bp0 + nt * 16 + ln;
      int pl = p & 1023;
      int jt = pl >> 6, jl = pl & 63;
#pragma unroll
      for (int i = 0; i < 4; ++i) {
        int oc = om + mt * 16 + qd * 4 + i;
        unsigned short val = f2bf(acc[mt][nt][i]);
        int bhead = b * 8 + (oc >> 5), d = oc & 31;
        if (mat == 0) {
          int cd2 = (d >> 3) ^ ((jl >> 2) & 3);
          kt[((((size_t)(bhead * 16 + jt)) * 64 + jl) * 4 + cd2) * 8 + (d & 7)] = (short)val;
        } else {
          int jjs = ((jl & 15) << 2) | (jl >> 4);
          int cj = (jjs >> 3) ^ (d & 7);
          vt[((((size_t)(bhead * 16 + jt)) * 32 + d) * 8 + cj) * 8 + (jjs & 7)] = (short)val;
        }
      }
    }
}

// --- phase 5: attn (1024 vblocks) ------------------------------------------
__device__ __forceinline__ void attn_body(
    int vb, unsigned char* SM, const short* qt, const short* kt,
    const short* vt, short* aoh, short* aol)
{
  short (*Ks)[2048] = (short (*)[2048])SM;            // 8192 B
  short (*Vs)[2048] = (short (*)[2048])(SM + 8192);   // 8192 B
  short (*P)[16][72] = (short (*)[16][72])(SM + 16384); // 9216 B
  const int t    = threadIdx.x;
  const int w    = t >> 6;
  const int lane = t & 63;
  const int ln   = lane & 15;
  const int qd   = lane >> 4;
  const int bh   = vb >> 4;
  const int q0   = (vb & 15) * 64 + w * 16;

  const short* ktb = kt + (size_t)bh * 32768;
  const short* vtb = vt + (size_t)bh * 32768;

  bf16x8 aq = *(const bf16x8*)&qt[((size_t)(bh * 1024 + q0 + ln)) * 32 + qd * 8];

  f32x4 acc[2] = {};
  float lacc[4] = {};
  const f32x4 zero = {0.f, 0.f, 0.f, 0.f};

  const int stoff = w * 512 + lane * 8;
  const int ldoff = w * 512;

  async_copy16(&ktb[stoff], &Ks[0][ldoff]);
  async_copy16(&vtb[stoff], &Vs[0][ldoff]);
  __syncthreads();

  for (int jt = 0; jt < 16; ++jt) {
    const int cur = jt & 1, nxt = cur ^ 1;
    if (jt < 15) {
      async_copy16(&ktb[(jt + 1) * 2048 + stoff], &Ks[nxt][ldoff]);
      async_copy16(&vtb[(jt + 1) * 2048 + stoff], &Vs[nxt][ldoff]);
    }

    bf16x8 bk[4], bv[2][2];
#pragma unroll
    for (int kk = 0; kk < 4; ++kk)
      bk[kk] = *(const bf16x8*)&Ks[cur][((kk * 16 + ln) * 4 + (qd ^ ((ln >> 2) & 3))) * 8];
#pragma unroll
    for (int kc = 0; kc < 2; ++kc)
#pragma unroll
      for (int ds = 0; ds < 2; ++ds)
        bv[kc][ds] = *(const bf16x8*)&Vs[cur][((ds * 16 + ln) * 8 + ((kc * 4 + qd) ^ (ln & 7))) * 8];

    f32x4 s[4];
#pragma unroll
    for (int kk = 0; kk < 4; ++kk)
      s[kk] = __builtin_amdgcn_mfma_f32_16x16x32_bf16(aq, bk[kk], zero, 0, 0, 0);

#pragma unroll
    for (int i = 0; i < 4; ++i) {
      float p0 = __builtin_amdgcn_exp2f(s[0][i]);
      float p1 = __builtin_amdgcn_exp2f(s[1][i]);
      float p2 = __builtin_amdgcn_exp2f(s[2][i]);
      float p3 = __builtin_amdgcn_exp2f(s[3][i]);
      s[0][i] = p0; s[1][i] = p1; s[2][i] = p2; s[3][i] = p3;
      lacc[i] += (p0 + p1) + (p2 + p3);
    }
#pragma unroll
    for (int i = 0; i < 4; ++i) {
      bf16x4 p4;
#pragma unroll
      for (int kk = 0; kk < 4; ++kk) p4[kk] = (short)f2bf_fast(s[kk][i]);
      *(bf16x4*)&P[w][qd * 4 + i][4 * ln] = p4;
    }
#pragma unroll
    for (int kc = 0; kc < 2; ++kc) {
      bf16x8 ap = *(const bf16x8*)&P[w][ln][kc * 32 + qd * 8];
#pragma unroll
      for (int ds = 0; ds < 2; ++ds)
        acc[ds] = __builtin_amdgcn_mfma_f32_16x16x32_bf16(ap, bv[kc][ds], acc[ds], 0, 0, 0);
    }

    __syncthreads();
  }

  const int b = bh >> 3, h = bh & 7;
#pragma unroll
  for (int i = 0; i < 4; ++i) {
    float l = lacc[i];
    l += __shfl_xor(l, 1, 64);
    l += __shfl_xor(l, 2, 64);
    l += __shfl_xor(l, 4, 64);
    l += __shfl_xor(l, 8, 64);
    float inv = 1.f / l;
    int qrow = q0 + qd * 4 + i;
#pragma unroll
    for (int ds = 0; ds < 2; ++ds) {
      float v = acc[ds][i] * inv;
      unsigned short hh = f2bf(v);
      size_t idx = ((size_t)(b * 1024 + qrow)) * 256 + h * 32 + ds * 16 + ln;
      aoh[idx] = (short)hh;
      aol[idx] = (short)f2bf(v - bf2f(hh));
    }
  }
}

// --- phase 6: gemm_out (256 vblocks, MODE 3, LDS-free) ---------------------
__device__ __forceinline__ void gemm_out_body(
    int bx, const short* Wh, const short* Wl,
    const short* Xh, const short* Xl, const float* bias, float* Yf)
{
  const int t    = threadIdx.x;
  const int w    = t >> 6;
  const int lane = t & 63;
  const int ln   = lane & 15;
  const int qd   = lane >> 4;
  const int bp0  = bx * 32;
  const int om   = w * 64;

  f32x4 acc[4][2] = {};
#pragma unroll
  for (int k0 = 0; k0 < 256; k0 += 32) {
    bf16x8 Ah[4], Al[4], Bh[2], Bl[2];
#pragma unroll
    for (int mt = 0; mt < 4; ++mt) {
      size_t wi = ((size_t)(om + mt * 16 + ln)) * 256 + k0 + qd * 8;
      Ah[mt] = *(const bf16x8*)&Wh[wi];
      Al[mt] = *(const bf16x8*)&Wl[wi];
    }
#pragma unroll
    for (int nt = 0; nt < 2; ++nt) {
      size_t xi = ((size_t)(bp0 + nt * 16 + ln)) * 256 + k0 + qd * 8;
      Bh[nt] = *(const bf16x8*)&Xh[xi];
      Bl[nt] = *(const bf16x8*)&Xl[xi];
    }
#pragma unroll
    for (int mt = 0; mt < 4; ++mt)
#pragma unroll
      for (int nt = 0; nt < 2; ++nt) {
        acc[mt][nt] = __builtin_amdgcn_mfma_f32_16x16x32_bf16(Ah[mt], Bh[nt], acc[mt][nt], 0, 0, 0);
        acc[mt][nt] = __builtin_amdgcn_mfma_f32_16x16x32_bf16(Ah[mt], Bl[nt], acc[mt][nt], 0, 0, 0);
        acc[mt][nt] = __builtin_amdgcn_mfma_f32_16x16x32_bf16(Al[mt], Bh[nt], acc[mt][nt], 0, 0, 0);
      }
  }

#pragma unroll
  for (int mt = 0; mt < 4; ++mt)
#pragma unroll
    for (int i = 0; i < 4; ++i) {
      int o = om + mt * 16 + qd * 4 + i;
      float bo = bias[o];
#pragma unroll
      for (int nt = 0; nt < 2; ++nt) {
        int bp = bp0 + nt * 16 + ln;
        int b = bp >> 10, p = bp & 1023;
        Yf[((size_t)(b * 256 + o)) * HW_ + p] = acc[mt][nt][i] + bo;
      }
    }
}

// ===========================================================================
// Cooperative mega-kernel: 6 phases, grid.sync() between. Grid 512 (2/CU),
// block 256, LDS 33792 B (union). Launch-gap + tail elimination.
// ===========================================================================
__global__ __launch_bounds__(256, 2) void mega(
    const float* query_map, const float* kv_map,
    const float* Wq, const float* Wk, const float* Wv,
    const float* Woff1, const float* boff1,
    const float* Woff2, const float* boff2,
    const float* Wout, const float* bout, float* out,
    float2* coords, short* qt, short* kt, short* vt,
    short* bufBh, short* bufBl, short* wb,
    short* WH, short* WL, float* kvT)
{
  __shared__ __align__(16) unsigned char SM[33792];
  cg::grid_group grid = cg::this_grid();
  const int nb = gridDim.x;

  // Phase 1: prep (2432 vblocks)
  for (int vb = blockIdx.x; vb < 2432; vb += nb) {
    prep_body(vb, SM, kv_map, Wq, Wk, Wv, Wout, Woff1, WH, WL, wb, kvT);
    __syncthreads();
  }
  grid.sync();

  // Phase 2: gemm_q (256 vblocks)
  if (blockIdx.x < 256)
    gemm_q_body(blockIdx.x, SM, WH, WL, query_map, qt, bufBh, bufBl);
  grid.sync();

  // Phase 3: conv + offsets (256 vblocks)
  if (blockIdx.x < 256)
    conv_body(blockIdx.x, SM, wb, boff1, Woff2, boff2, bufBh, bufBl, coords);
  grid.sync();

  // Phase 4: gemm_kv (512 vblocks)
  gemm_kv_body(blockIdx.x, SM, WH, WL, kvT, coords, kt, vt);
  grid.sync();

  // Phase 5: attention (1024 vblocks -> 2 iterations)
  for (int vb = blockIdx.x; vb < 1024; vb += nb) {
    attn_body(vb, SM, qt, kt, vt, bufBh, bufBl);
    __syncthreads();
  }
  grid.sync();

  // Phase 6: gemm_out (256 vblocks)
  if (blockIdx.x < 256)
    gemm_out_body(blockIdx.x, WH + 196608, WL + 196608, bufBh, bufBl, bout, out);
}

// ---------------------------------------------------------------------------
extern "C" void kernel_launch(void* const* d_in, const int* in_sizes, int n_in,
                              void* d_out, int out_size, void* d_ws, size_t ws_size,
                              hipStream_t stream)
{
  const float* query_map = (const float*)d_in[0];
  const float* kv_map    = (const float*)d_in[1];
  const float* Wq        = (const float*)d_in[2];
  const float* Wk        = (const float*)d_in[3];
  const float* Wv        = (const float*)d_in[4];
  const float* Woff1     = (const float*)d_in[5];
  const float* boff1     = (const float*)d_in[6];
  const float* Woff2     = (const float*)d_in[7];
  const float* boff2     = (const float*)d_in[8];
  const float* Wout      = (const float*)d_in[9];
  const float* bout      = (const float*)d_in[10];
  float* out = (float*)d_out;
  char* base = (char*)d_ws;

  const size_t MB = 1u << 20;
  float2* coords = (float2*)(base);             // 64 KB
  short* qt     = (short*)(base + 1 * MB);      // 4 MB (bh,p,d) pre-scaled
  short* kt     = (short*)(base + 5 * MB);      // 4 MB tiled+swizzled
  short* vt     = (short*)(base + 9 * MB);      // 4 MB tiled+swizzled
  short* bufBh  = (short*)(base + 13 * MB);     // 4 MB q hi -> ao hi
  short* bufBl  = (short*)(base + 17 * MB);     // 4 MB q lo -> ao lo
  short* wb     = (short*)(base + 21 * MB);     // 576 KB conv weights bf16
  short* WH     = (short*)(base + 22 * MB);     // 512 KB W hi
  short* WL     = (short*)(base + 23 * MB);     // 512 KB W lo
  float* kvT    = (float*)(base + 24 * MB);     // 8 MB kv_map (b,p,c) f32

  void* args[] = {
    (void*)&query_map, (void*)&kv_map, (void*)&Wq, (void*)&Wk, (void*)&Wv,
    (void*)&Woff1, (void*)&boff1, (void*)&Woff2, (void*)&boff2,
    (void*)&Wout, (void*)&bout, (void*)&out,
    (void*)&coords, (void*)&qt, (void*)&kt, (void*)&vt,
    (void*)&bufBh, (void*)&bufBl, (void*)&wb,
    (void*)&WH, (void*)&WL, (void*)&kvT
  };
  hipLaunchCooperativeKernel((const void*)mega, dim3(512), dim3(256),
                             args, 0, stream);
}

// Round 15
// 199.215 us; speedup vs baseline: 2.4803x; 2.4803x over previous
//
#include <hip/hip_runtime.h>

#define HW_ 1024

typedef __attribute__((ext_vector_type(8))) short bf16x8;   // 8 bf16 = 4 VGPRs
typedef __attribute__((ext_vector_type(4))) short bf16x4;   // 8 B
typedef __attribute__((ext_vector_type(4))) float f32x4;

__device__ inline unsigned short f2bf(float f) {            // RNE f32->bf16
  unsigned int u = __float_as_uint(f);
  u += 0x7FFF + ((u >> 16) & 1);
  return (unsigned short)(u >> 16);
}
__device__ inline unsigned short f2bf_fast(float f) {       // ties-away (2 ops)
  return (unsigned short)((__float_as_uint(f) + 0x8000u) >> 16);
}
__device__ inline float bf2f(unsigned short h) {
  return __uint_as_float(((unsigned int)h) << 16);
}
__device__ inline void async_copy16(const void* g, void* l) {
  __builtin_amdgcn_global_load_lds(
      (const __attribute__((address_space(1))) unsigned int*)g,
      (__attribute__((address_space(3))) unsigned int*)l, 16, 0, 0);
}

// ---------------------------------------------------------------------------
// prep (r13): [0,256) kvT transpose via LDS tile; [256,1280) wsplit;
// [1280,2432) conv weights.
// ---------------------------------------------------------------------------
__global__ __launch_bounds__(256) void prep(
    const float* __restrict__ kv,
    const float* __restrict__ W0, const float* __restrict__ W1,
    const float* __restrict__ W2, const float* __restrict__ W3,
    const float* __restrict__ Woff1,
    short* __restrict__ WH, short* __restrict__ WL, short* __restrict__ wb,
    float* __restrict__ kvT)
{
  __shared__ float T[256][33];
  const int bid = blockIdx.x, t = threadIdx.x;
  if (bid < 256) {                      // kvT: (b,c,p) -> (b,p,c) f32
    int b = bid >> 5, p0 = (bid & 31) * 32;
    int pp = t & 31, cg = t >> 5;
#pragma unroll
    for (int i = 0; i < 32; ++i) {
      int c = cg * 32 + i;
      T[c][pp] = kv[((size_t)(b * 256 + c)) * HW_ + p0 + pp];
    }
    __syncthreads();
#pragma unroll
    for (int r = 0; r < 8; ++r) {
      int e = t + 256 * r;
      int c4 = (e & 63) * 4, pp2 = e >> 6;
      float4 v4;
      v4.x = T[c4 + 0][pp2];
      v4.y = T[c4 + 1][pp2];
      v4.z = T[c4 + 2][pp2];
      v4.w = T[c4 + 3][pp2];
      *(float4*)&kvT[((size_t)(b * 1024 + p0 + pp2)) * 256 + c4] = v4;
    }
  } else if (bid < 1280) {              // wsplit
    int b2 = bid - 256;
    int mat = b2 >> 8;
    int idx = (b2 & 255) * 256 + t;
    const float* W = (mat == 0) ? W0 : (mat == 1) ? W1 : (mat == 2) ? W2 : W3;
    float f = W[idx];
    unsigned short h = f2bf(f);
    WH[mat * 65536 + idx] = (short)h;
    WL[mat * 65536 + idx] = (short)f2bf(f - bf2f(h));
  } else {                              // wprep conv weights
    int e = (bid - 1280) * 256 + t;     // < 294912
    int c = e & 255;
    int o = (e >> 8) & 127;
    int tap = e >> 15;
    wb[e] = (short)f2bf(Woff1[((size_t)(o * 256 + c)) * 9 + tap]);
  }
}

// ---------------------------------------------------------------------------
// MFMA GEMM, M=256 K=256 N=8192, 3-pass split bf16 (~fp32).
// NOW grid (256, 2): blockIdx.y picks M half; wave tile M=32 (mt=2),
// 512 blocks = 2 blocks/CU (halved serial chain, doubled latency hiding).
// A-fragments from precomputed bf16 WH/WL (single b128 load — r11's f32
// in-register split is NOT repeated; it regressed).
// MODE 0: X = query_map f32 (b,c,p) staged+split via LDS; outputs qt + q hi/lo.
// MODE 3: X = (b,p,c) hi/lo bf16 LDS-free; f32 out + bias.
// ---------------------------------------------------------------------------
template <int MODE>
__global__ __launch_bounds__(256) void gemm_mfma(
    const short* __restrict__ Wh, const short* __restrict__ Wl,
    const float* __restrict__ Xf,
    const short* __restrict__ Xh, const short* __restrict__ Xl,
    const float* __restrict__ bias, float* __restrict__ Yf,
    short* __restrict__ Yt, short* __restrict__ Yh2, short* __restrict__ Yl2)
{
  __shared__ short Bsh[32][40];   // [p][c] pad 40 (80B rows: 16B-aligned)
  __shared__ short Bsl[32][40];
  const int t    = threadIdx.x;
  const int w    = t >> 6;
  const int lane = t & 63;
  const int ln   = lane & 15;
  const int qd   = lane >> 4;
  const int bp0  = blockIdx.x * 32;
  const int om   = blockIdx.y * 128 + w * 32;   // wave M-tile = 32
  const int bB   = bp0 >> 10, p0l = bp0 & 1023;

  f32x4 acc[2][2] = {};
#pragma unroll
  for (int k0 = 0; k0 < 256; k0 += 32) {
    bf16x8 Ah[2], Al[2], Bh[2], Bl[2];
    if (MODE == 0) {                    // stage + split X tile (both y-blocks)
      __syncthreads();
      int pp = t & 31, cg = t >> 5;     // cg 0..7, 4 c's each
      float fv[4];
#pragma unroll
      for (int j = 0; j < 4; ++j)
        fv[j] = Xf[((size_t)(bB * 256 + k0 + cg * 4 + j)) * HW_ + p0l + pp];
      bf16x4 h4, l4;
#pragma unroll
      for (int j = 0; j < 4; ++j) {
        unsigned short h = f2bf(fv[j]);
        h4[j] = (short)h;
        l4[j] = (short)f2bf(fv[j] - bf2f(h));
      }
      *(bf16x4*)&Bsh[pp][cg * 4] = h4;
      *(bf16x4*)&Bsl[pp][cg * 4] = l4;
      __syncthreads();
    }
#pragma unroll
    for (int mt = 0; mt < 2; ++mt) {
      size_t wi = ((size_t)(om + mt * 16 + ln)) * 256 + k0 + qd * 8;
      Ah[mt] = *(const bf16x8*)&Wh[wi];
      Al[mt] = *(const bf16x8*)&Wl[wi];
    }
    if (MODE == 0) {
#pragma unroll
      for (int nt = 0; nt < 2; ++nt) {
        Bh[nt] = *(const bf16x8*)&Bsh[nt * 16 + ln][qd * 8];
        Bl[nt] = *(const bf16x8*)&Bsl[nt * 16 + ln][qd * 8];
      }
    } else {
#pragma unroll
      for (int nt = 0; nt < 2; ++nt) {
        size_t xi = ((size_t)(bp0 + nt * 16 + ln)) * 256 + k0 + qd * 8;
        Bh[nt] = *(const bf16x8*)&Xh[xi];
        Bl[nt] = *(const bf16x8*)&Xl[xi];
      }
    }
#pragma unroll
    for (int mt = 0; mt < 2; ++mt)
#pragma unroll
      for (int nt = 0; nt < 2; ++nt) {
        acc[mt][nt] = __builtin_amdgcn_mfma_f32_16x16x32_bf16(Ah[mt], Bh[nt], acc[mt][nt], 0, 0, 0);
        acc[mt][nt] = __builtin_amdgcn_mfma_f32_16x16x32_bf16(Ah[mt], Bl[nt], acc[mt][nt], 0, 0, 0);
        acc[mt][nt] = __builtin_amdgcn_mfma_f32_16x16x32_bf16(Al[mt], Bh[nt], acc[mt][nt], 0, 0, 0);
      }
  }

  if (MODE == 3) {
#pragma unroll
    for (int mt = 0; mt < 2; ++mt)
#pragma unroll
      for (int i = 0; i < 4; ++i) {
        int o = om + mt * 16 + qd * 4 + i;
        float bo = bias[o];
#pragma unroll
        for (int nt = 0; nt < 2; ++nt) {
          int bp = bp0 + nt * 16 + ln;
          int b = bp >> 10, p = bp & 1023;
          Yf[((size_t)(b * 256 + o)) * HW_ + p] = acc[mt][nt][i] + bo;
        }
      }
  }
  if (MODE == 0) {
    const float sc = 0.25506063286f;   // (1/sqrt32)*log2(e)
#pragma unroll
    for (int mt = 0; mt < 2; ++mt)
#pragma unroll
      for (int nt = 0; nt < 2; ++nt) {
        int bp = bp0 + nt * 16 + ln;
        int b = bp >> 10, p = bp & 1023;
#pragma unroll
        for (int i = 0; i < 4; ++i) {
          int o = om + mt * 16 + qd * 4 + i;
          int h = o >> 5, d = o & 31;
          Yt[(((size_t)(b * 8 + h)) * 1024 + p) * 32 + d] = (short)f2bf(acc[mt][nt][i] * sc);
        }
        int ob = om + mt * 16 + qd * 4;
        bf16x4 h4, l4;
#pragma unroll
        for (int i = 0; i < 4; ++i) {
          float f = acc[mt][nt][i];
          unsigned short h = f2bf(f);
          h4[i] = (short)h;
          l4[i] = (short)f2bf(f - bf2f(h));
        }
        *(bf16x4*)&Yh2[(size_t)bp * 256 + ob] = h4;
        *(bf16x4*)&Yl2[(size_t)bp * 256 + ob] = l4;
      }
  }
}

// ---------------------------------------------------------------------------
// conv3x3 (split-bf16 MFMA) fused with offset head (unchanged r13).
// ---------------------------------------------------------------------------
__global__ __launch_bounds__(256) void conv3x3_off(
    const short* __restrict__ wb, const float* __restrict__ bias,
    const float* __restrict__ W2, const float* __restrict__ b2,
    const short* __restrict__ xh, const short* __restrict__ xl,
    float2* __restrict__ coords)
{
  __shared__ short Xs[2][3][34][32];
  __shared__ float red[4][32][2];
  const int t    = threadIdx.x;
  const int w    = t >> 6;
  const int lane = t & 63;
  const int ln   = lane & 15;
  const int qd   = lane >> 4;
  const int y0   = blockIdx.x;
  const int b    = blockIdx.y;
  const int o0   = w * 32;

  f32x4 acc[2][2] = {};

  for (int c0 = 0; c0 < 256; c0 += 32) {
    __syncthreads();
#pragma unroll
    for (int i = 0; i < 3; ++i) {
      int e   = t + 256 * i;
      int oct = e & 3;
      int x   = (e >> 2) & 31;
      int r   = (e >> 7) % 3;
      int hl  = e / 384;
      int yy  = y0 + r - 1;
      bf16x8 val = {};
      if (yy >= 0 && yy < 32) {
        const short* src = hl ? xl : xh;
        val = *(const bf16x8*)&src[((size_t)((b * 32 + yy) * 32 + x)) * 256 + c0 + oct * 8];
      }
      *(bf16x8*)&Xs[hl][r][x + 1][oct * 8] = val;
    }
    if (t < 48) {
      int oct = t & 3;
      int col = ((t >> 2) & 1) ? 33 : 0;
      int r   = (t >> 3) % 3;
      int hl  = t / 24;
      bf16x8 z = {};
      *(bf16x8*)&Xs[hl][r][col][oct * 8] = z;
    }
    __syncthreads();

#pragma unroll
    for (int tap = 0; tap < 9; ++tap) {
      const int ky = tap / 3, kx = tap % 3;
      bf16x8 afr[2];
#pragma unroll
      for (int m = 0; m < 2; ++m)
        afr[m] = *(const bf16x8*)&wb[((size_t)(tap * 128 + o0 + m * 16 + ln)) * 256
                                     + c0 + qd * 8];
#pragma unroll
      for (int nt = 0; nt < 2; ++nt) {
        int hc = nt * 16 + ln + kx;
        bf16x8 bh = *(const bf16x8*)&Xs[0][ky][hc][qd * 8];
        bf16x8 bl = *(const bf16x8*)&Xs[1][ky][hc][qd * 8];
#pragma unroll
        for (int m = 0; m < 2; ++m) {
          acc[m][nt] = __builtin_amdgcn_mfma_f32_16x16x32_bf16(afr[m], bh, acc[m][nt], 0, 0, 0);
          acc[m][nt] = __builtin_amdgcn_mfma_f32_16x16x32_bf16(afr[m], bl, acc[m][nt], 0, 0, 0);
        }
      }
    }
  }

  float ps0[2] = {0.f, 0.f}, ps1[2] = {0.f, 0.f};
#pragma unroll
  for (int m = 0; m < 2; ++m)
#pragma unroll
    for (int i = 0; i < 4; ++i) {
      int o = o0 + m * 16 + qd * 4 + i;
      float bo = bias[o];
      float w2a = W2[o], w2b = W2[128 + o];
#pragma unroll
      for (int nt = 0; nt < 2; ++nt) {
        float h = fmaxf(acc[m][nt][i] + bo, 0.f);
        ps0[nt] += w2a * h;
        ps1[nt] += w2b * h;
      }
    }
#pragma unroll
  for (int msk = 16; msk < 64; msk <<= 1) {
    ps0[0] += __shfl_xor(ps0[0], msk, 64);
    ps0[1] += __shfl_xor(ps0[1], msk, 64);
    ps1[0] += __shfl_xor(ps1[0], msk, 64);
    ps1[1] += __shfl_xor(ps1[1], msk, 64);
  }
  if (qd == 0) {
#pragma unroll
    for (int nt = 0; nt < 2; ++nt) {
      red[w][nt * 16 + ln][0] = ps0[nt];
      red[w][nt * 16 + ln][1] = ps1[nt];
    }
  }
  __syncthreads();
  if (t < 32) {
    int x = t;
    float s0 = red[0][x][0] + red[1][x][0] + red[2][x][0] + red[3][x][0] + b2[0];
    float s1 = red[0][x][1] + red[1][x][1] + red[2][x][1] + red[3][x][1] + b2[1];
    float gx = -1.f + 2.f * (float)x / 31.f;
    float gy = -1.f + 2.f * (float)y0 / 31.f;
    float vx = gx + 0.1f * s0;
    float vy = gy + 0.1f * s1;
    float px = fminf(fmaxf((vx + 1.f) * 0.5f * 31.f, 0.f), 31.f);
    float py = fminf(fmaxf((vy + 1.f) * 0.5f * 31.f, 0.f), 31.f);
    coords[b * 1024 + y0 * 32 + x] = make_float2(px, py);
  }
}

// ---------------------------------------------------------------------------
// K+V GEMM fused with bilinear sampling via kvT, grid (256,2) (unchanged r12/13).
// ---------------------------------------------------------------------------
__global__ __launch_bounds__(256) void gemm_kv(
    const short* __restrict__ WH, const short* __restrict__ WL,
    const float* __restrict__ kvT, const float2* __restrict__ coords,
    short* __restrict__ kt, short* __restrict__ vt)
{
  __shared__ short XsH[32][264];
  __shared__ short XsL[32][264];
  const int t   = threadIdx.x;
  const int bp0 = blockIdx.x * 32;
  const int b   = bp0 >> 10;
  const int mat = blockIdx.y;          // 0 = K, 1 = V

#pragma unroll
  for (int it = 0; it < 4; ++it) {
    int e = t + 256 * it;            // 1024 tasks: 32 rows x 32 octs
    int oct = e & 31, row = e >> 5;
    float2 cd = coords[bp0 + row];
    float x0f = floorf(cd.x), y0f = floorf(cd.y);
    float wx = cd.x - x0f, wy = cd.y - y0f;
    int x0 = (int)x0f, y0 = (int)y0f;
    int x1 = min(x0 + 1, 31), y1 = min(y0 + 1, 31);
    float w00 = (1.f - wx) * (1.f - wy), w01 = wx * (1.f - wy);
    float w10 = (1.f - wx) * wy,         w11 = wx * wy;
    const float* r00 = &kvT[((size_t)(b * 1024 + y0 * 32 + x0)) * 256 + oct * 8];
    const float* r01 = &kvT[((size_t)(b * 1024 + y0 * 32 + x1)) * 256 + oct * 8];
    const float* r10 = &kvT[((size_t)(b * 1024 + y1 * 32 + x0)) * 256 + oct * 8];
    const float* r11 = &kvT[((size_t)(b * 1024 + y1 * 32 + x1)) * 256 + oct * 8];
    float4 a00 = *(const float4*)r00, b00 = *(const float4*)(r00 + 4);
    float4 a01 = *(const float4*)r01, b01 = *(const float4*)(r01 + 4);
    float4 a10 = *(const float4*)r10, b10 = *(const float4*)(r10 + 4);
    float4 a11 = *(const float4*)r11, b11 = *(const float4*)(r11 + 4);
    float v[8];
    v[0] = a00.x * w00 + a01.x * w01 + a10.x * w10 + a11.x * w11;
    v[1] = a00.y * w00 + a01.y * w01 + a10.y * w10 + a11.y * w11;
    v[2] = a00.z * w00 + a01.z * w01 + a10.z * w10 + a11.z * w11;
    v[3] = a00.w * w00 + a01.w * w01 + a10.w * w10 + a11.w * w11;
    v[4] = b00.x * w00 + b01.x * w01 + b10.x * w10 + b11.x * w11;
    v[5] = b00.y * w00 + b01.y * w01 + b10.y * w10 + b11.y * w11;
    v[6] = b00.z * w00 + b01.z * w01 + b10.z * w10 + b11.z * w11;
    v[7] = b00.w * w00 + b01.w * w01 + b10.w * w10 + b11.w * w11;
    bf16x8 h8, l8;
#pragma unroll
    for (int j = 0; j < 8; ++j) {
      unsigned short h = f2bf(v[j]);
      h8[j] = (short)h;
      l8[j] = (short)f2bf(v[j] - bf2f(h));
    }
    *(bf16x8*)&XsH[row][oct * 8] = h8;
    *(bf16x8*)&XsL[row][oct * 8] = l8;
  }
  __syncthreads();

  const int w    = t >> 6;
  const int lane = t & 63;
  const int ln   = lane & 15;
  const int qd   = lane >> 4;
  const short* WAh = WH + (mat ? 131072 : 65536);   // Wv : Wk (bf16 hi)
  const short* WAl = WL + (mat ? 131072 : 65536);
  const int om = w * 64;               // wave covers 64 of the 256 rows

  f32x4 acc[4][2] = {};
#pragma unroll
  for (int k0 = 0; k0 < 256; k0 += 32) {
    bf16x8 Bh[2], Bl[2];
#pragma unroll
    for (int nt = 0; nt < 2; ++nt) {
      Bh[nt] = *(const bf16x8*)&XsH[nt * 16 + ln][k0 + qd * 8];
      Bl[nt] = *(const bf16x8*)&XsL[nt * 16 + ln][k0 + qd * 8];
    }
#pragma unroll
    for (int mt = 0; mt < 4; ++mt) {
      size_t wi = ((size_t)(om + mt * 16 + ln)) * 256 + k0 + qd * 8;
      bf16x8 Ah = *(const bf16x8*)&WAh[wi];
      bf16x8 Al = *(const bf16x8*)&WAl[wi];
#pragma unroll
      for (int nt = 0; nt < 2; ++nt) {
        acc[mt][nt] = __builtin_amdgcn_mfma_f32_16x16x32_bf16(Ah, Bh[nt], acc[mt][nt], 0, 0, 0);
        acc[mt][nt] = __builtin_amdgcn_mfma_f32_16x16x32_bf16(Ah, Bl[nt], acc[mt][nt], 0, 0, 0);
        acc[mt][nt] = __builtin_amdgcn_mfma_f32_16x16x32_bf16(Al, Bh[nt], acc[mt][nt], 0, 0, 0);
      }
    }
  }

#pragma unroll
  for (int mt = 0; mt < 4; ++mt)
#pragma unroll
    for (int nt = 0; nt < 2; ++nt) {
      int p  = bp0 + nt * 16 + ln;
      int pl = p & 1023;
      int jt = pl >> 6, jl = pl & 63;
#pragma unroll
      for (int i = 0; i < 4; ++i) {
        int oc = om + mt * 16 + qd * 4 + i;      // channel within K or V
        unsigned short val = f2bf(acc[mt][nt][i]);
        int bhead = b * 8 + (oc >> 5), d = oc & 31;
        if (mat == 0) {
          int cd2 = (d >> 3) ^ ((jl >> 2) & 3);
          kt[((((size_t)(bhead * 16 + jt)) * 64 + jl) * 4 + cd2) * 8 + (d & 7)] = (short)val;
        } else {
          int jjs = ((jl & 15) << 2) | (jl >> 4);       // sigma
          int cj = (jjs >> 3) ^ (d & 7);
          vt[((((size_t)(bhead * 16 + jt)) * 32 + d) * 8 + cj) * 8 + (jjs & 7)] = (short)val;
        }
      }
    }
}

// ---------------------------------------------------------------------------
// MFMA flash attention with async LDS double-buffered K/V (unchanged r10).
// grid (16, 64), block 256.
// ---------------------------------------------------------------------------
__global__ __launch_bounds__(256) void attn_mfma(
    const short* __restrict__ qt, const short* __restrict__ kt,
    const short* __restrict__ vt, short* __restrict__ aoh,
    short* __restrict__ aol)
{
  __shared__ __align__(16) short Ks[2][2048];
  __shared__ __align__(16) short Vs[2][2048];
  __shared__ __align__(16) short P[4][16][72];
  const int t    = threadIdx.x;
  const int w    = t >> 6;
  const int lane = t & 63;
  const int ln   = lane & 15;
  const int qd   = lane >> 4;
  const int bh   = blockIdx.y;
  const int q0   = blockIdx.x * 64 + w * 16;

  const short* ktb = kt + (size_t)bh * 32768;
  const short* vtb = vt + (size_t)bh * 32768;

  bf16x8 aq = *(const bf16x8*)&qt[((size_t)(bh * 1024 + q0 + ln)) * 32 + qd * 8];

  f32x4 acc[2] = {};
  float lacc[4] = {};
  const f32x4 zero = {0.f, 0.f, 0.f, 0.f};

  const int stoff = w * 512 + lane * 8;
  const int ldoff = w * 512;

  async_copy16(&ktb[stoff], &Ks[0][ldoff]);
  async_copy16(&vtb[stoff], &Vs[0][ldoff]);
  __syncthreads();

  for (int jt = 0; jt < 16; ++jt) {
    const int cur = jt & 1, nxt = cur ^ 1;
    if (jt < 15) {
      async_copy16(&ktb[(jt + 1) * 2048 + stoff], &Ks[nxt][ldoff]);
      async_copy16(&vtb[(jt + 1) * 2048 + stoff], &Vs[nxt][ldoff]);
    }

    bf16x8 bk[4], bv[2][2];
#pragma unroll
    for (int kk = 0; kk < 4; ++kk)
      bk[kk] = *(const bf16x8*)&Ks[cur][((kk * 16 + ln) * 4 + (qd ^ ((ln >> 2) & 3))) * 8];
#pragma unroll
    for (int kc = 0; kc < 2; ++kc)
#pragma unroll
      for (int ds = 0; ds < 2; ++ds)
        bv[kc][ds] = *(const bf16x8*)&Vs[cur][((ds * 16 + ln) * 8 + ((kc * 4 + qd) ^ (ln & 7))) * 8];

    f32x4 s[4];
#pragma unroll
    for (int kk = 0; kk < 4; ++kk)
      s[kk] = __builtin_amdgcn_mfma_f32_16x16x32_bf16(aq, bk[kk], zero, 0, 0, 0);

#pragma unroll
    for (int i = 0; i < 4; ++i) {
      float p0 = __builtin_amdgcn_exp2f(s[0][i]);
      float p1 = __builtin_amdgcn_exp2f(s[1][i]);
      float p2 = __builtin_amdgcn_exp2f(s[2][i]);
      float p3 = __builtin_amdgcn_exp2f(s[3][i]);
      s[0][i] = p0; s[1][i] = p1; s[2][i] = p2; s[3][i] = p3;
      lacc[i] += (p0 + p1) + (p2 + p3);
    }
#pragma unroll
    for (int i = 0; i < 4; ++i) {
      bf16x4 p4;
#pragma unroll
      for (int kk = 0; kk < 4; ++kk) p4[kk] = (short)f2bf_fast(s[kk][i]);
      *(bf16x4*)&P[w][qd * 4 + i][4 * ln] = p4;
    }
#pragma unroll
    for (int kc = 0; kc < 2; ++kc) {
      bf16x8 ap = *(const bf16x8*)&P[w][ln][kc * 32 + qd * 8];
#pragma unroll
      for (int ds = 0; ds < 2; ++ds)
        acc[ds] = __builtin_amdgcn_mfma_f32_16x16x32_bf16(ap, bv[kc][ds], acc[ds], 0, 0, 0);
    }

    __syncthreads();
  }

  const int b = bh >> 3, h = bh & 7;
#pragma unroll
  for (int i = 0; i < 4; ++i) {
    float l = lacc[i];
    l += __shfl_xor(l, 1, 64);
    l += __shfl_xor(l, 2, 64);
    l += __shfl_xor(l, 4, 64);
    l += __shfl_xor(l, 8, 64);
    float inv = 1.f / l;
    int qrow = q0 + qd * 4 + i;
#pragma unroll
    for (int ds = 0; ds < 2; ++ds) {
      float v = acc[ds][i] * inv;
      unsigned short hh = f2bf(v);
      size_t idx = ((size_t)(b * 1024 + qrow)) * 256 + h * 32 + ds * 16 + ln;
      aoh[idx] = (short)hh;
      aol[idx] = (short)f2bf(v - bf2f(hh));
    }
  }
}

// ---------------------------------------------------------------------------
extern "C" void kernel_launch(void* const* d_in, const int* in_sizes, int n_in,
                              void* d_out, int out_size, void* d_ws, size_t ws_size,
                              hipStream_t stream)
{
  const float* query_map = (const float*)d_in[0];
  const float* kv_map    = (const float*)d_in[1];
  const float* Wq        = (const float*)d_in[2];
  const float* Wk        = (const float*)d_in[3];
  const float* Wv        = (const float*)d_in[4];
  const float* Woff1     = (const float*)d_in[5];
  const float* boff1     = (const float*)d_in[6];
  const float* Woff2     = (const float*)d_in[7];
  const float* boff2     = (const float*)d_in[8];
  const float* Wout      = (const float*)d_in[9];
  const float* bout      = (const float*)d_in[10];
  float* out = (float*)d_out;
  char* base = (char*)d_ws;

  const size_t MB = 1u << 20;
  float* coords = (float*)(base);              // 64 KB
  short* qt     = (short*)(base + 1 * MB);     // 4 MB (bh,p,d) pre-scaled
  short* kt     = (short*)(base + 5 * MB);     // 4 MB tiled+swizzled
  short* vt     = (short*)(base + 9 * MB);     // 4 MB tiled+swizzled
  short* bufBh  = (short*)(base + 13 * MB);    // 4 MB q hi -> ao hi
  short* bufBl  = (short*)(base + 17 * MB);    // 4 MB q lo -> ao lo
  short* wb     = (short*)(base + 21 * MB);    // 576 KB conv weights bf16
  short* WH     = (short*)(base + 22 * MB);    // 512 KB Wq/Wk/Wv/Wout hi
  short* WL     = (short*)(base + 23 * MB);    // 512 KB lo
  float* kvT    = (float*)(base + 24 * MB);    // 8 MB kv_map (b,p,c) f32

  dim3 blk(256);
  prep<<<dim3(2432), blk, 0, stream>>>(kv_map, Wq, Wk, Wv, Wout, Woff1,
                                       WH, WL, wb, kvT);
  gemm_mfma<0><<<dim3(256, 2), blk, 0, stream>>>(WH, WL, query_map, nullptr, nullptr,
                                                 nullptr, nullptr, qt, bufBh, bufBl);
  conv3x3_off<<<dim3(32, 8), blk, 0, stream>>>(wb, boff1, Woff2, boff2,
                                               bufBh, bufBl, (float2*)coords);
  gemm_kv<<<dim3(256, 2), blk, 0, stream>>>(WH, WL, kvT, (const float2*)coords, kt, vt);
  attn_mfma<<<dim3(16, 64), blk, 0, stream>>>(qt, kt, vt, bufBh, bufBl);
  gemm_mfma<3><<<dim3(256, 2), blk, 0, stream>>>(WH + 196608, WL + 196608, nullptr,
                                                 bufBh, bufBl, bout, out,
                                                 nullptr, nullptr, nullptr);
}